// Round 3
// 250.385 us; speedup vs baseline: 1.0549x; 1.0549x over previous
//
#include <hip/hip_runtime.h>
#include <stdint.h>

typedef float f32x4 __attribute__((ext_vector_type(4)));  // native vec for nontemporal

// Factored algorithm:
//   ref: pre = [hs|hd|bond] @ W1^T + b1 + (hs+hd) @ W2^T + b2
//   =>  pre[e,o] = hs.(W1a[o]+W2[o]) + hd.(W1b[o]+W2[o]) + bond[e]*W1c[o] + (b1+b2)[o]
//   node tables: A = atom @ (W1a+W2)^T, B = atom @ (W1b+W2)^T   (N=10k << E=320k)
//   edge pass:   out[e] = leaky(A[src[e]] + B[dst[e]] + bond[e]*c + bias)

// ---------------------------------------------------------------------------
// prep: fused weights, stored KC-MAJOR so node_kernel's per-lane row reads
// coalesce: Wf_t[kc][r] (kc = k>>2 in [0,32), r in [0,256), float4 chunks).
//   float index: Wf[kc*1024 + r*4 + (k&3)]
//   row r < 128  : U[r][k] = W1[r,k]       + W2[r,k]
//   row 128+r    : V[r][k] = W1[r,128+k]   + W2[r,k]
//   cb[0:128]   = c[o]    = W1[o,256]
//   cb[128:256] = bias[o] = b1[o] + b2[o]
// ---------------------------------------------------------------------------
__global__ __launch_bounds__(256) void prep_kernel(
    const float* __restrict__ W1, const float* __restrict__ b1,
    const float* __restrict__ W2, const float* __restrict__ b2,
    float* __restrict__ Wf, float* __restrict__ cb)
{
    int idx = blockIdx.x * 256 + threadIdx.x;
    if (idx < 32768) {
        int r = idx >> 7, k = idx & 127;
        float w2 = W2[(r & 127) * 128 + k];
        float w1 = (r < 128) ? W1[r * 257 + k]
                             : W1[(r - 128) * 257 + 128 + k];
        int kc = k >> 2, j = k & 3;
        Wf[kc * 1024 + r * 4 + j] = w1 + w2;   // kc-major (transposed) layout
    }
    if (idx < 128) {
        cb[idx]       = W1[idx * 257 + 256];
        cb[128 + idx] = b1[idx] + b2[idx];
    }
}

// ---------------------------------------------------------------------------
// node transform: A[n][o] = atom[n,:].U[o,:] ; B[n][o] = atom[n,:].V[o,:]
// 256 threads: thread t owns fused-weight row t (t<128 -> A, else B).
// 8 nodes per block (N=10000 -> 1250 blocks, ~4.9 waves/SIMD for latency
// hiding). Weight reads COALESCED: wt[kc*256 + t] -> 64 lanes read 1 KB
// contiguous per instruction (was 64 scattered lines at stride 512 B).
// Atom-row reads are block-uniform -> L1 broadcast.
// ---------------------------------------------------------------------------
#define NODES_PER_BLOCK 8
__global__ __launch_bounds__(256) void node_kernel(
    const float* __restrict__ atom, const float* __restrict__ Wf,
    float* __restrict__ A, float* __restrict__ B, int N)
{
    const int t = threadIdx.x;
    const float4* __restrict__ wt = (const float4*)Wf;      // [32][256] float4
    const float4* __restrict__ arows = (const float4*)atom; // [N][32] float4
    const int base = blockIdx.x * NODES_PER_BLOCK;
    if (base >= N) return;

    float acc[NODES_PER_BLOCK];
#pragma unroll
    for (int n = 0; n < NODES_PER_BLOCK; ++n) acc[n] = 0.f;

#pragma unroll 4
    for (int kc = 0; kc < 32; ++kc) {
        float4 w = wt[kc * 256 + t];
#pragma unroll
        for (int n = 0; n < NODES_PER_BLOCK; ++n) {
            int row = base + n;
            if (row >= N) row = N - 1;  // uniform clamp: harmless dup work
            float4 a = arows[(size_t)row * 32 + kc];
            acc[n] += w.x * a.x + w.y * a.y + w.z * a.z + w.w * a.w;
        }
    }

    float* outp = (t < 128) ? A : B;
    const int o = t & 127;
#pragma unroll
    for (int n = 0; n < NODES_PER_BLOCK; ++n) {
        int row = base + n;
        if (row < N) outp[(size_t)row * 128 + o] = acc[n];
    }
}

// ---------------------------------------------------------------------------
// edge pass: out[e,:] = leaky(A[src[e]] + B[dst[e]] + bond[e]*c + bias)
// 32 lanes per edge, 8 edges per 256-thread block; each lane does one float4
// of the 128-wide row -> 512 B contiguous per edge row.
// Output written with NONTEMPORAL stores: 163.8 MB write-once data; keep it
// out of L2 so the 4 MiB/XCD L2 holds the A/B gather tables instead.
// ---------------------------------------------------------------------------
__global__ __launch_bounds__(256) void edge_kernel(
    const int* __restrict__ src, const int* __restrict__ dst,
    const float* __restrict__ bond,
    const float* __restrict__ A, const float* __restrict__ B,
    const float* __restrict__ cb, f32x4* __restrict__ out, int E)
{
    const int g = threadIdx.x >> 5;
    const int l = threadIdx.x & 31;
    const int e = blockIdx.x * 8 + g;
    if (e >= E) return;

    const int s = src[e];          // same addr across the 32-lane group:
    const int d = dst[e];          // broadcast, L1-served
    const float bv = bond[e];

    float4 a  = ((const float4*)A)[(size_t)s * 32 + l];
    float4 b  = ((const float4*)B)[(size_t)d * 32 + l];
    float4 c  = ((const float4*)cb)[l];
    float4 bi = ((const float4*)cb)[32 + l];

    f32x4 x;
    x.x = a.x + b.x + bv * c.x + bi.x;
    x.y = a.y + b.y + bv * c.y + bi.y;
    x.z = a.z + b.z + bv * c.z + bi.z;
    x.w = a.w + b.w + bv * c.w + bi.w;
    x.x = x.x > 0.f ? x.x : 0.01f * x.x;
    x.y = x.y > 0.f ? x.y : 0.01f * x.y;
    x.z = x.z > 0.f ? x.z : 0.01f * x.z;
    x.w = x.w > 0.f ? x.w : 0.01f * x.w;

    __builtin_nontemporal_store(x, &out[(size_t)e * 32 + l]);
}

// ---------------------------------------------------------------------------
extern "C" void kernel_launch(void* const* d_in, const int* in_sizes, int n_in,
                              void* d_out, int out_size, void* d_ws, size_t ws_size,
                              hipStream_t stream)
{
    const float* atom = (const float*)d_in[0];  // [N,128] fp32
    const float* bond = (const float*)d_in[1];  // [E,1]  fp32
    const int*   src  = (const int*)d_in[2];    // [E]
    const int*   dst  = (const int*)d_in[3];    // [E]
    const float* W1   = (const float*)d_in[4];  // [128,257] fp32
    const float* b1   = (const float*)d_in[5];  // [128]
    const float* W2   = (const float*)d_in[6];  // [128,128] fp32
    const float* b2   = (const float*)d_in[7];  // [128]

    const int N = in_sizes[0] / 128;
    const int E = in_sizes[2];

    // workspace layout (fp32): Wf[256*128] | cb[256] | A[N*128] | B[N*128]
    // total = (32768 + 256 + 2*N*128)*4 B ~= 10.4 MB for N=10000
    float* Wf = (float*)d_ws;
    float* cb = Wf + 32768;
    float* A  = cb + 256;
    float* B  = A + (size_t)N * 128;

    prep_kernel<<<128, 256, 0, stream>>>(W1, b1, W2, b2, Wf, cb);
    node_kernel<<<(N + NODES_PER_BLOCK - 1) / NODES_PER_BLOCK, 256, 0, stream>>>(
        atom, Wf, A, B, N);
    edge_kernel<<<(E + 7) / 8, 256, 0, stream>>>(src, dst, bond, A, B, cb,
                                                 (f32x4*)d_out, E);
}

// Round 4
// 244.786 us; speedup vs baseline: 1.0790x; 1.0229x over previous
//
#include <hip/hip_runtime.h>
#include <stdint.h>

typedef float f32x4 __attribute__((ext_vector_type(4)));  // native vec for nontemporal

// Factored algorithm:
//   ref: pre = [hs|hd|bond] @ W1^T + b1 + (hs+hd) @ W2^T + b2
//   =>  pre[e,o] = hs.(W1a[o]+W2[o]) + hd.(W1b[o]+W2[o]) + bond[e]*W1c[o] + (b1+b2)[o]
//   node tables: A = atom @ (W1a+W2)^T + bias, B = atom @ (W1b+W2)^T
//   edge pass:   out[e] = leaky(A[src[e]] + B[dst[e]] + bond[e]*c)
//   (bias folded into A so the edge pass reads one fewer vector)

// ---------------------------------------------------------------------------
// prep: fused weights, stored KC-MAJOR so node_kernel's per-lane row reads
// coalesce: Wf_t[kc][r] (kc = k>>2 in [0,32), r in [0,256), float4 chunks).
//   float index: Wf[kc*1024 + r*4 + (k&3)]
//   row r < 128  : U[r][k] = W1[r,k]       + W2[r,k]
//   row 128+r    : V[r][k] = W1[r,128+k]   + W2[r,k]
//   cb[0:128]   = c[o]    = W1[o,256]
//   cb[128:256] = bias[o] = b1[o] + b2[o]
// ---------------------------------------------------------------------------
__global__ __launch_bounds__(256) void prep_kernel(
    const float* __restrict__ W1, const float* __restrict__ b1,
    const float* __restrict__ W2, const float* __restrict__ b2,
    float* __restrict__ Wf, float* __restrict__ cb)
{
    int idx = blockIdx.x * 256 + threadIdx.x;
    if (idx < 32768) {
        int r = idx >> 7, k = idx & 127;
        float w2 = W2[(r & 127) * 128 + k];
        float w1 = (r < 128) ? W1[r * 257 + k]
                             : W1[(r - 128) * 257 + 128 + k];
        int kc = k >> 2, j = k & 3;
        Wf[kc * 1024 + r * 4 + j] = w1 + w2;   // kc-major (transposed) layout
    }
    if (idx < 128) {
        cb[idx]       = W1[idx * 257 + 256];
        cb[128 + idx] = b1[idx] + b2[idx];
    }
}

// ---------------------------------------------------------------------------
// node transform: A[n][o] = atom[n,:].U[o,:] + bias[o] ; B[n][o] = atom[n,:].V[o,:]
// 256 threads: thread t owns fused-weight row t (t<128 -> A, else B).
// 8 nodes per block. Weight reads coalesced (1 KB/instr); atom reads are
// wave-uniform broadcasts (L1). Bias folded into A at store time.
// ---------------------------------------------------------------------------
#define NODES_PER_BLOCK 8
__global__ __launch_bounds__(256) void node_kernel(
    const float* __restrict__ atom, const float* __restrict__ Wf,
    const float* __restrict__ cb,
    float* __restrict__ A, float* __restrict__ B, int N)
{
    const int t = threadIdx.x;
    const float4* __restrict__ wt = (const float4*)Wf;      // [32][256] float4
    const float4* __restrict__ arows = (const float4*)atom; // [N][32] float4
    const int base = blockIdx.x * NODES_PER_BLOCK;
    if (base >= N) return;

    const int o = t & 127;
    const float badd = (t < 128) ? cb[128 + o] : 0.f;  // bias -> A only

    float acc[NODES_PER_BLOCK];
#pragma unroll
    for (int n = 0; n < NODES_PER_BLOCK; ++n) acc[n] = 0.f;

#pragma unroll 4
    for (int kc = 0; kc < 32; ++kc) {
        float4 w = wt[kc * 256 + t];
#pragma unroll
        for (int n = 0; n < NODES_PER_BLOCK; ++n) {
            int row = base + n;
            if (row >= N) row = N - 1;  // uniform clamp: harmless dup work
            float4 a = arows[(size_t)row * 32 + kc];
            acc[n] += w.x * a.x + w.y * a.y + w.z * a.z + w.w * a.w;
        }
    }

    float* outp = (t < 128) ? A : B;
#pragma unroll
    for (int n = 0; n < NODES_PER_BLOCK; ++n) {
        int row = base + n;
        if (row < N) outp[(size_t)row * 128 + o] = acc[n] + badd;
    }
}

// ---------------------------------------------------------------------------
// edge pass: out[e,:] = leaky(A[src[e]] + B[dst[e]] + bond[e]*c)
// 32 lanes per edge-slot; each group handles TWO edges so 4 independent
// 512 B gathers are in flight per group (2x the memory-level parallelism of
// one-edge-per-group). 16 edges per 256-thread block. Index loads (6) are
// issued before any gather; output written with nontemporal stores to keep
// the write-once 164 MB stream out of L2 (L2 holds the A/B tables).
// ---------------------------------------------------------------------------
__global__ __launch_bounds__(256) void edge_kernel(
    const int* __restrict__ src, const int* __restrict__ dst,
    const float* __restrict__ bond,
    const float* __restrict__ A, const float* __restrict__ B,
    const float* __restrict__ cb, f32x4* __restrict__ out, int E)
{
    const int g = threadIdx.x >> 5;
    const int l = threadIdx.x & 31;
    const int e0 = blockIdx.x * 16 + g * 2;
    if (e0 >= E) return;
    const int e1 = e0 + 1;
    const bool has1 = (e1 < E);

    // all index loads up front (independent, single round trip)
    const int   s0 = src[e0];
    const int   d0 = dst[e0];
    const float v0 = bond[e0];
    const int   s1 = has1 ? src[e1] : s0;
    const int   d1 = has1 ? dst[e1] : d0;
    const float v1 = has1 ? bond[e1] : v0;

    const float4* __restrict__ A4 = (const float4*)A;
    const float4* __restrict__ B4 = (const float4*)B;

    // 4 independent gathers in flight
    float4 a0 = A4[(size_t)s0 * 32 + l];
    float4 b0 = B4[(size_t)d0 * 32 + l];
    float4 a1 = A4[(size_t)s1 * 32 + l];
    float4 b1 = B4[(size_t)d1 * 32 + l];
    float4 c  = ((const float4*)cb)[l];     // L1-hot

    f32x4 x0, x1;
    x0.x = a0.x + b0.x + v0 * c.x;
    x0.y = a0.y + b0.y + v0 * c.y;
    x0.z = a0.z + b0.z + v0 * c.z;
    x0.w = a0.w + b0.w + v0 * c.w;
    x1.x = a1.x + b1.x + v1 * c.x;
    x1.y = a1.y + b1.y + v1 * c.y;
    x1.z = a1.z + b1.z + v1 * c.z;
    x1.w = a1.w + b1.w + v1 * c.w;

    x0.x = x0.x > 0.f ? x0.x : 0.01f * x0.x;
    x0.y = x0.y > 0.f ? x0.y : 0.01f * x0.y;
    x0.z = x0.z > 0.f ? x0.z : 0.01f * x0.z;
    x0.w = x0.w > 0.f ? x0.w : 0.01f * x0.w;
    x1.x = x1.x > 0.f ? x1.x : 0.01f * x1.x;
    x1.y = x1.y > 0.f ? x1.y : 0.01f * x1.y;
    x1.z = x1.z > 0.f ? x1.z : 0.01f * x1.z;
    x1.w = x1.w > 0.f ? x1.w : 0.01f * x1.w;

    __builtin_nontemporal_store(x0, &out[(size_t)e0 * 32 + l]);
    if (has1)
        __builtin_nontemporal_store(x1, &out[(size_t)e1 * 32 + l]);
}

// ---------------------------------------------------------------------------
extern "C" void kernel_launch(void* const* d_in, const int* in_sizes, int n_in,
                              void* d_out, int out_size, void* d_ws, size_t ws_size,
                              hipStream_t stream)
{
    const float* atom = (const float*)d_in[0];  // [N,128] fp32
    const float* bond = (const float*)d_in[1];  // [E,1]  fp32
    const int*   src  = (const int*)d_in[2];    // [E]
    const int*   dst  = (const int*)d_in[3];    // [E]
    const float* W1   = (const float*)d_in[4];  // [128,257] fp32
    const float* b1   = (const float*)d_in[5];  // [128]
    const float* W2   = (const float*)d_in[6];  // [128,128] fp32
    const float* b2   = (const float*)d_in[7];  // [128]

    const int N = in_sizes[0] / 128;
    const int E = in_sizes[2];

    // workspace layout (fp32): Wf[256*128] | cb[256] | A[N*128] | B[N*128]
    // total = (32768 + 256 + 2*N*128)*4 B ~= 10.4 MB for N=10000
    float* Wf = (float*)d_ws;
    float* cb = Wf + 32768;
    float* A  = cb + 256;
    float* B  = A + (size_t)N * 128;

    prep_kernel<<<128, 256, 0, stream>>>(W1, b1, W2, b2, Wf, cb);
    node_kernel<<<(N + NODES_PER_BLOCK - 1) / NODES_PER_BLOCK, 256, 0, stream>>>(
        atom, Wf, cb, A, B, N);
    edge_kernel<<<(E + 15) / 16, 256, 0, stream>>>(src, dst, bond, A, B, cb,
                                                   (f32x4*)d_out, E);
}

// Round 5
// 241.824 us; speedup vs baseline: 1.0922x; 1.0122x over previous
//
#include <hip/hip_runtime.h>
#include <stdint.h>

typedef float f32x4 __attribute__((ext_vector_type(4)));  // native vec for nontemporal

// Factored algorithm:
//   ref: pre = [hs|hd|bond] @ W1^T + b1 + (hs+hd) @ W2^T + b2
//   =>  pre[e,o] = hs.(W1a[o]+W2[o]) + hd.(W1b[o]+W2[o]) + bond[e]*W1c[o] + (b1+b2)[o]
//   node tables: A = atom @ (W1a+W2)^T + bias, B = atom @ (W1b+W2)^T
//   edge pass:   out[e] = leaky(A[src[e]] + B[dst[e]] + bond[e]*c)
//   (bias folded into A so the edge pass reads one fewer vector)

// ---------------------------------------------------------------------------
// prep: fused weights, stored KC-MAJOR so node_kernel's per-lane row reads
// coalesce: Wf_t[kc][r] (kc = k>>2 in [0,32), r in [0,256), float4 chunks).
//   float index: Wf[kc*1024 + r*4 + (k&3)]
//   row r < 128  : U[r][k] = W1[r,k]       + W2[r,k]
//   row 128+r    : V[r][k] = W1[r,128+k]   + W2[r,k]
//   cb[0:128]   = c[o]    = W1[o,256]
//   cb[128:256] = bias[o] = b1[o] + b2[o]
// ---------------------------------------------------------------------------
__global__ __launch_bounds__(256) void prep_kernel(
    const float* __restrict__ W1, const float* __restrict__ b1,
    const float* __restrict__ W2, const float* __restrict__ b2,
    float* __restrict__ Wf, float* __restrict__ cb)
{
    int idx = blockIdx.x * 256 + threadIdx.x;
    if (idx < 32768) {
        int r = idx >> 7, k = idx & 127;
        float w2 = W2[(r & 127) * 128 + k];
        float w1 = (r < 128) ? W1[r * 257 + k]
                             : W1[(r - 128) * 257 + 128 + k];
        int kc = k >> 2, j = k & 3;
        Wf[kc * 1024 + r * 4 + j] = w1 + w2;   // kc-major (transposed) layout
    }
    if (idx < 128) {
        cb[idx]       = W1[idx * 257 + 256];
        cb[128 + idx] = b1[idx] + b2[idx];
    }
}

// ---------------------------------------------------------------------------
// node transform: A[n][o] = atom[n,:].U[o,:] + bias[o] ; B[n][o] = atom[n,:].V[o,:]
// 256 threads: thread t owns fused-weight row t (t<128 -> A, else B).
// 8 nodes per block. Weight reads coalesced (1 KB/instr); atom reads are
// wave-uniform broadcasts (L1). Bias folded into A at store time.
// ---------------------------------------------------------------------------
#define NODES_PER_BLOCK 8
__global__ __launch_bounds__(256) void node_kernel(
    const float* __restrict__ atom, const float* __restrict__ Wf,
    const float* __restrict__ cb,
    float* __restrict__ A, float* __restrict__ B, int N)
{
    const int t = threadIdx.x;
    const float4* __restrict__ wt = (const float4*)Wf;      // [32][256] float4
    const float4* __restrict__ arows = (const float4*)atom; // [N][32] float4
    const int base = blockIdx.x * NODES_PER_BLOCK;
    if (base >= N) return;

    const int o = t & 127;
    const float badd = (t < 128) ? cb[128 + o] : 0.f;  // bias -> A only

    float acc[NODES_PER_BLOCK];
#pragma unroll
    for (int n = 0; n < NODES_PER_BLOCK; ++n) acc[n] = 0.f;

#pragma unroll 4
    for (int kc = 0; kc < 32; ++kc) {
        float4 w = wt[kc * 256 + t];
#pragma unroll
        for (int n = 0; n < NODES_PER_BLOCK; ++n) {
            int row = base + n;
            if (row >= N) row = N - 1;  // uniform clamp: harmless dup work
            float4 a = arows[(size_t)row * 32 + kc];
            acc[n] += w.x * a.x + w.y * a.y + w.z * a.z + w.w * a.w;
        }
    }

    float* outp = (t < 128) ? A : B;
#pragma unroll
    for (int n = 0; n < NODES_PER_BLOCK; ++n) {
        int row = base + n;
        if (row < N) outp[(size_t)row * 128 + o] = acc[n] + badd;
    }
}

// ---------------------------------------------------------------------------
// edge pass: out[e,:] = leaky(A[src[e]] + B[dst[e]] + bond[e]*c)
// 32 lanes per edge-slot; each group handles FOUR edges -> 8 independent
// 512 B gathers in flight per group. 32 edges per 256-thread block. All
// index loads issued before any gather (one round trip). Output written
// with nontemporal stores: write-once 164 MB stays out of L2, leaving L2
// for the A/B gather tables.
// ---------------------------------------------------------------------------
__global__ __launch_bounds__(256) void edge_kernel(
    const int* __restrict__ src, const int* __restrict__ dst,
    const float* __restrict__ bond,
    const float* __restrict__ A, const float* __restrict__ B,
    const float* __restrict__ cb, f32x4* __restrict__ out, int E)
{
    const int g = threadIdx.x >> 5;
    const int l = threadIdx.x & 31;
    const int e0 = blockIdx.x * 32 + g * 4;
    if (e0 >= E) return;
    const int e1 = e0 + 1, e2 = e0 + 2, e3 = e0 + 3;
    const bool h1 = e1 < E, h2 = e2 < E, h3 = e3 < E;

    // all index loads up front (independent, single round trip)
    const int   s0 = src[e0];
    const int   d0 = dst[e0];
    const float v0 = bond[e0];
    const int   s1 = h1 ? src[e1] : s0;
    const int   d1 = h1 ? dst[e1] : d0;
    const float v1 = h1 ? bond[e1] : v0;
    const int   s2 = h2 ? src[e2] : s0;
    const int   d2 = h2 ? dst[e2] : d0;
    const float v2 = h2 ? bond[e2] : v0;
    const int   s3 = h3 ? src[e3] : s0;
    const int   d3 = h3 ? dst[e3] : d0;
    const float v3 = h3 ? bond[e3] : v0;

    const float4* __restrict__ A4 = (const float4*)A;
    const float4* __restrict__ B4 = (const float4*)B;

    // 8 independent gathers in flight
    float4 a0 = A4[(size_t)s0 * 32 + l];
    float4 b0 = B4[(size_t)d0 * 32 + l];
    float4 a1 = A4[(size_t)s1 * 32 + l];
    float4 b1 = B4[(size_t)d1 * 32 + l];
    float4 a2 = A4[(size_t)s2 * 32 + l];
    float4 b2 = B4[(size_t)d2 * 32 + l];
    float4 a3 = A4[(size_t)s3 * 32 + l];
    float4 b3 = B4[(size_t)d3 * 32 + l];
    float4 c  = ((const float4*)cb)[l];     // L1-hot

    f32x4 x0, x1, x2, x3;
    x0.x = a0.x + b0.x + v0 * c.x;  x0.y = a0.y + b0.y + v0 * c.y;
    x0.z = a0.z + b0.z + v0 * c.z;  x0.w = a0.w + b0.w + v0 * c.w;
    x1.x = a1.x + b1.x + v1 * c.x;  x1.y = a1.y + b1.y + v1 * c.y;
    x1.z = a1.z + b1.z + v1 * c.z;  x1.w = a1.w + b1.w + v1 * c.w;
    x2.x = a2.x + b2.x + v2 * c.x;  x2.y = a2.y + b2.y + v2 * c.y;
    x2.z = a2.z + b2.z + v2 * c.z;  x2.w = a2.w + b2.w + v2 * c.w;
    x3.x = a3.x + b3.x + v3 * c.x;  x3.y = a3.y + b3.y + v3 * c.y;
    x3.z = a3.z + b3.z + v3 * c.z;  x3.w = a3.w + b3.w + v3 * c.w;

    x0.x = x0.x > 0.f ? x0.x : 0.01f * x0.x;
    x0.y = x0.y > 0.f ? x0.y : 0.01f * x0.y;
    x0.z = x0.z > 0.f ? x0.z : 0.01f * x0.z;
    x0.w = x0.w > 0.f ? x0.w : 0.01f * x0.w;
    x1.x = x1.x > 0.f ? x1.x : 0.01f * x1.x;
    x1.y = x1.y > 0.f ? x1.y : 0.01f * x1.y;
    x1.z = x1.z > 0.f ? x1.z : 0.01f * x1.z;
    x1.w = x1.w > 0.f ? x1.w : 0.01f * x1.w;
    x2.x = x2.x > 0.f ? x2.x : 0.01f * x2.x;
    x2.y = x2.y > 0.f ? x2.y : 0.01f * x2.y;
    x2.z = x2.z > 0.f ? x2.z : 0.01f * x2.z;
    x2.w = x2.w > 0.f ? x2.w : 0.01f * x2.w;
    x3.x = x3.x > 0.f ? x3.x : 0.01f * x3.x;
    x3.y = x3.y > 0.f ? x3.y : 0.01f * x3.y;
    x3.z = x3.z > 0.f ? x3.z : 0.01f * x3.z;
    x3.w = x3.w > 0.f ? x3.w : 0.01f * x3.w;

    __builtin_nontemporal_store(x0, &out[(size_t)e0 * 32 + l]);
    if (h1) __builtin_nontemporal_store(x1, &out[(size_t)e1 * 32 + l]);
    if (h2) __builtin_nontemporal_store(x2, &out[(size_t)e2 * 32 + l]);
    if (h3) __builtin_nontemporal_store(x3, &out[(size_t)e3 * 32 + l]);
}

// ---------------------------------------------------------------------------
extern "C" void kernel_launch(void* const* d_in, const int* in_sizes, int n_in,
                              void* d_out, int out_size, void* d_ws, size_t ws_size,
                              hipStream_t stream)
{
    const float* atom = (const float*)d_in[0];  // [N,128] fp32
    const float* bond = (const float*)d_in[1];  // [E,1]  fp32
    const int*   src  = (const int*)d_in[2];    // [E]
    const int*   dst  = (const int*)d_in[3];    // [E]
    const float* W1   = (const float*)d_in[4];  // [128,257] fp32
    const float* b1   = (const float*)d_in[5];  // [128]
    const float* W2   = (const float*)d_in[6];  // [128,128] fp32
    const float* b2   = (const float*)d_in[7];  // [128]

    const int N = in_sizes[0] / 128;
    const int E = in_sizes[2];

    // workspace layout (fp32): Wf[256*128] | cb[256] | A[N*128] | B[N*128]
    // total = (32768 + 256 + 2*N*128)*4 B ~= 10.4 MB for N=10000
    float* Wf = (float*)d_ws;
    float* cb = Wf + 32768;
    float* A  = cb + 256;
    float* B  = A + (size_t)N * 128;

    prep_kernel<<<128, 256, 0, stream>>>(W1, b1, W2, b2, Wf, cb);
    node_kernel<<<(N + NODES_PER_BLOCK - 1) / NODES_PER_BLOCK, 256, 0, stream>>>(
        atom, Wf, cb, A, B, N);
    edge_kernel<<<(E + 31) / 32, 256, 0, stream>>>(src, dst, bond, A, B, cb,
                                                   (f32x4*)d_out, E);
}